// Round 12
// baseline (413.905 us; speedup 1.0000x reference)
//
#include <hip/hip_runtime.h>

#define N_NODES 50000
#define N_EDGES 800000
#define D_INF 64
#define D_HIDF 128

#define NBUCKET ((N_NODES + 63) / 64)          // 782 buckets of 64 dst nodes
#define CHUNK 4096
#define NCHUNK ((N_EDGES + CHUNK - 1) / CHUNK) // 196 sort-fill blocks

typedef __attribute__((ext_vector_type(8))) short bf16x8v;
typedef __attribute__((ext_vector_type(4))) float f32x4;

__device__ __forceinline__ ushort f2bf(float f) {
    unsigned int u = __builtin_bit_cast(unsigned int, f);
    u += 0x7FFF + ((u >> 16) & 1);  // RNE
    return (ushort)(u >> 16);
}
__device__ __forceinline__ float bf2f(ushort u) {
    return __builtin_bit_cast(float, ((unsigned int)u) << 16);
}

// ---------------------------------------------------------------------------
// K1: fused prep — x->bf16, weight transpose->bf16, zero bucket counters.
// ---------------------------------------------------------------------------

#define CVT_N (N_NODES * D_INF / 8)   // 400000
#define PREP_N (D_INF * D_HIDF)       // 8192

__global__ void prep_kernel(const float* __restrict__ x, ushort* __restrict__ xb,
                            const float* __restrict__ W1, const float* __restrict__ W2,
                            ushort* __restrict__ w1tb, ushort* __restrict__ w2tb,
                            int* __restrict__ cnt_g) {
    int gid = blockIdx.x * blockDim.x + threadIdx.x;
    if (gid < CVT_N) {
        float4 a = reinterpret_cast<const float4*>(x)[gid * 2];
        float4 b = reinterpret_cast<const float4*>(x)[gid * 2 + 1];
        ushort o[8] = {f2bf(a.x), f2bf(a.y), f2bf(a.z), f2bf(a.w),
                       f2bf(b.x), f2bf(b.y), f2bf(b.z), f2bf(b.w)};
        *reinterpret_cast<ulonglong2*>(xb + gid * 8) = *reinterpret_cast<ulonglong2*>(o);
    } else if (gid < CVT_N + PREP_N) {
        int i = gid - CVT_N;
        int j = i >> 6, l = i & 63;
        w1tb[i] = f2bf(W1[l * D_HIDF + j]);
        int d = i >> 7, jj = i & 127;
        w2tb[i] = f2bf(W2[jj * D_INF + d]);
    } else if (gid < CVT_N + PREP_N + NBUCKET) {
        cnt_g[gid - CVT_N - PREP_N] = 0;
    }
}

// ---------------------------------------------------------------------------
// K2: per-block LDS histogram of dst buckets -> global cnt_g
// ---------------------------------------------------------------------------

__global__ void __launch_bounds__(256) hist_kernel(const int* __restrict__ dst,
                                                   int* __restrict__ cnt_g) {
    __shared__ int cnt[NBUCKET];
    int t = threadIdx.x;
    for (int i = t; i < NBUCKET; i += 256) cnt[i] = 0;
    __syncthreads();
    int base = blockIdx.x * CHUNK;
#pragma unroll
    for (int k = 0; k < CHUNK / 256; k++) {
        int e = base + k * 256 + t;
        if (e < N_EDGES) atomicAdd(&cnt[dst[e] >> 6], 1);
    }
    __syncthreads();
    for (int i = t; i < NBUCKET; i += 256) {
        int c = cnt[i];
        if (c) atomicAdd(&cnt_g[i], c);
    }
}

// ---------------------------------------------------------------------------
// K3: single-block exclusive scan of cnt_g[782] -> base_g, gcursor
// ---------------------------------------------------------------------------

__global__ void __launch_bounds__(256) scan_kernel(const int* __restrict__ cnt_g,
                                                   int* __restrict__ base_g,
                                                   int* __restrict__ gcursor) {
    __shared__ int wsum[4];
    int t = threadIdx.x;
    int lane = t & 63;
    int wv = t >> 6;
    int b0 = t * 4;
    int v[4];
    int s = 0;
#pragma unroll
    for (int i = 0; i < 4; i++) {
        v[i] = (b0 + i < NBUCKET) ? cnt_g[b0 + i] : 0;
        s += v[i];
    }
    int incl = s;
#pragma unroll
    for (int off = 1; off < 64; off <<= 1) {
        int u = __shfl_up(incl, off);
        if (lane >= off) incl += u;
    }
    if (lane == 63) wsum[wv] = incl;
    __syncthreads();
    if (t == 0) { wsum[1] += wsum[0]; wsum[2] += wsum[1]; wsum[3] += wsum[2]; }
    __syncthreads();
    int run = ((wv > 0) ? wsum[wv - 1] : 0) + (incl - s);
#pragma unroll
    for (int i = 0; i < 4; i++) {
        if (b0 + i < NBUCKET) {
            base_g[b0 + i] = run;
            gcursor[b0 + i] = run;
        }
        run += v[i];
    }
}

// ---------------------------------------------------------------------------
// K4: sort-fill. Each block counting-sorts its 4096-edge chunk by bucket in
// LDS, reserves contiguous global ranges (1 atomic per block-bucket), then
// writes binned[] in contiguous runs. pack = (dst<<16)|src (both < 65536).
// ---------------------------------------------------------------------------

__global__ void __launch_bounds__(256) sortfill_kernel(const int* __restrict__ src,
                                                       const int* __restrict__ dst,
                                                       int* __restrict__ gcursor,
                                                       unsigned int* __restrict__ binned) {
    __shared__ int cnt[NBUCKET];
    __shared__ int off[NBUCKET];
    __shared__ int cur[NBUCKET];
    __shared__ int gbase[NBUCKET];
    __shared__ unsigned int buf[CHUNK];
    __shared__ int wsum[4];

    int t = threadIdx.x;
    int lane = t & 63;
    int wv = t >> 6;
    int base = blockIdx.x * CHUNK;
    int chunk_n = min(CHUNK, N_EDGES - base);

    for (int i = t; i < NBUCKET; i += 256) cnt[i] = 0;
    __syncthreads();

    // pass 1: count
#pragma unroll
    for (int k = 0; k < CHUNK / 256; k++) {
        int e = base + k * 256 + t;
        if (e < N_EDGES) atomicAdd(&cnt[dst[e] >> 6], 1);
    }
    __syncthreads();

    // scan (782 elems, 4/thread) + global reservation
    {
        int b0 = t * 4;
        int v[4];
        int s = 0;
#pragma unroll
        for (int i = 0; i < 4; i++) {
            v[i] = (b0 + i < NBUCKET) ? cnt[b0 + i] : 0;
            s += v[i];
        }
        int incl = s;
#pragma unroll
        for (int o = 1; o < 64; o <<= 1) {
            int u = __shfl_up(incl, o);
            if (lane >= o) incl += u;
        }
        if (lane == 63) wsum[wv] = incl;
        __syncthreads();
        if (t == 0) { wsum[1] += wsum[0]; wsum[2] += wsum[1]; wsum[3] += wsum[2]; }
        __syncthreads();
        int run = ((wv > 0) ? wsum[wv - 1] : 0) + (incl - s);
#pragma unroll
        for (int i = 0; i < 4; i++) {
            int b = b0 + i;
            if (b < NBUCKET) {
                off[b] = run;
                cur[b] = run;
                if (v[i] > 0) gbase[b] = atomicAdd(&gcursor[b], v[i]);
            }
            run += v[i];
        }
    }
    __syncthreads();

    // pass 2: place into LDS buffer sorted by bucket
#pragma unroll
    for (int k = 0; k < CHUNK / 256; k++) {
        int e = base + k * 256 + t;
        if (e < N_EDGES) {
            int d = dst[e];
            int s = src[e];
            int b = d >> 6;
            int r = atomicAdd(&cur[b], 1);
            buf[r] = ((unsigned int)d << 16) | (unsigned int)s;
        }
    }
    __syncthreads();

    // pass 3: contiguous-run writeout
#pragma unroll
    for (int k = 0; k < CHUNK / 256; k++) {
        int slot = k * 256 + t;
        if (slot < chunk_n) {
            unsigned int pk = buf[slot];
            int b = pk >> 22;
            binned[gbase[b] + (slot - off[b])] = pk;
        }
    }
}

// ---------------------------------------------------------------------------
// K5: tile gather. One block per bucket; 64-node f32 agg tile in LDS
// (init = self term from xb); waves stream contiguous edge sub-segments with
// independent x-row loads (no chains) + ds_add_f32. Output bf16.
// ---------------------------------------------------------------------------

__global__ void __launch_bounds__(256) tile_gather_kernel(
    const ushort* __restrict__ xb, const unsigned int* __restrict__ binned,
    const int* __restrict__ base_g, const int* __restrict__ cnt_g,
    ushort* __restrict__ aggb)
{
    __shared__ float tile[64 * D_INF];  // 16 KB
    int t = threadIdx.x;
    int lane = t & 63;
    int wv = t >> 6;
    int b = blockIdx.x;
    int nb = b * 64;

    // init tile with self term (bf16 x), zero for OOB rows
#pragma unroll
    for (int k = 0; k < 16; k++) {
        int i = k * 256 + t;   // i = row*64 + col
        int node = nb + (i >> 6);
        tile[i] = (node < N_NODES) ? bf2f(xb[(size_t)nb * D_INF + i]) : 0.f;
    }
    __syncthreads();

    int beg = base_g[b];
    int cnt = cnt_g[b];
    int per = (cnt + 3) >> 2;
    int e = beg + wv * per;
    int eend = min(e + per, beg + cnt);

    for (; e + 3 < eend; e += 4) {
        unsigned int p0 = binned[e + 0];
        unsigned int p1 = binned[e + 1];
        unsigned int p2 = binned[e + 2];
        unsigned int p3 = binned[e + 3];
        float v0 = bf2f(xb[(size_t)(p0 & 0xFFFFu) * D_INF + lane]);
        float v1 = bf2f(xb[(size_t)(p1 & 0xFFFFu) * D_INF + lane]);
        float v2 = bf2f(xb[(size_t)(p2 & 0xFFFFu) * D_INF + lane]);
        float v3 = bf2f(xb[(size_t)(p3 & 0xFFFFu) * D_INF + lane]);
        atomicAdd(&tile[((p0 >> 16) & 63u) * D_INF + lane], v0);
        atomicAdd(&tile[((p1 >> 16) & 63u) * D_INF + lane], v1);
        atomicAdd(&tile[((p2 >> 16) & 63u) * D_INF + lane], v2);
        atomicAdd(&tile[((p3 >> 16) & 63u) * D_INF + lane], v3);
    }
    for (; e < eend; e++) {
        unsigned int p = binned[e];
        float v = bf2f(xb[(size_t)(p & 0xFFFFu) * D_INF + lane]);
        atomicAdd(&tile[((p >> 16) & 63u) * D_INF + lane], v);
    }
    __syncthreads();

    // writeout bf16
#pragma unroll
    for (int k = 0; k < 16; k++) {
        int i = k * 256 + t;
        int node = nb + (i >> 6);
        if (node < N_NODES) aggb[(size_t)nb * D_INF + i] = f2bf(tile[i]);
    }
}

// ---------------------------------------------------------------------------
// K6: MLP (MFMA), unchanged from round 8 (proven).
// ---------------------------------------------------------------------------

#define AT_LD 72
#define W1_LD 72
#define HT_LD 136
#define W2_LD 136

__global__ void __launch_bounds__(256) mlp_mfma_kernel(
    const ushort* __restrict__ aggb, const ushort* __restrict__ w1tb,
    const float* __restrict__ b1v, const ushort* __restrict__ w2tb,
    const float* __restrict__ b2v, float* __restrict__ out)
{
    __shared__ __align__(16) ushort atile[64 * AT_LD];
    __shared__ __align__(16) ushort w1s[128 * W1_LD];
    __shared__ __align__(16) ushort w2s[64 * W2_LD];
    __shared__ __align__(16) ushort htile[64 * HT_LD];

    int tid = threadIdx.x;
    int lane = tid & 63;
    int wv = tid >> 6;
    int nb = blockIdx.x * 64;

#pragma unroll
    for (int c = 0; c < 2; c++) {
        int chunk = tid + c * 256;
        int row = chunk >> 3;
        int col = (chunk & 7) * 8;
        ulonglong2 v;
        v.x = 0; v.y = 0;
        if (nb + row < N_NODES)
            v = *reinterpret_cast<const ulonglong2*>(aggb + (size_t)(nb + row) * D_INF + col);
        *reinterpret_cast<ulonglong2*>(&atile[row * AT_LD + col]) = v;
    }
#pragma unroll
    for (int c = 0; c < 4; c++) {
        int chunk = tid + c * 256;
        int row = chunk >> 3;
        int col = (chunk & 7) * 8;
        *reinterpret_cast<ulonglong2*>(&w1s[row * W1_LD + col]) =
            *reinterpret_cast<const ulonglong2*>(w1tb + row * 64 + col);
    }
#pragma unroll
    for (int c = 0; c < 4; c++) {
        int chunk = tid + c * 256;
        int row = chunk >> 4;
        int col = (chunk & 15) * 8;
        *reinterpret_cast<ulonglong2*>(&w2s[row * W2_LD + col]) =
            *reinterpret_cast<const ulonglong2*>(w2tb + row * 128 + col);
    }
    __syncthreads();

    int q = lane >> 4;
    int m = lane & 15;
    int arow = wv * 16 + m;
    int hrow0 = wv * 16 + q * 4;

    // GEMM1: H = A @ W1
    bf16x8v a0 = *reinterpret_cast<const bf16x8v*>(&atile[arow * AT_LD + q * 8]);
    bf16x8v a1 = *reinterpret_cast<const bf16x8v*>(&atile[arow * AT_LD + 32 + q * 8]);
#pragma unroll
    for (int jt = 0; jt < 8; jt++) {
        int j = jt * 16 + m;
        bf16x8v bf0 = *reinterpret_cast<const bf16x8v*>(&w1s[j * W1_LD + q * 8]);
        bf16x8v bf1 = *reinterpret_cast<const bf16x8v*>(&w1s[j * W1_LD + 32 + q * 8]);
        f32x4 acc = {0.f, 0.f, 0.f, 0.f};
        acc = __builtin_amdgcn_mfma_f32_16x16x32_bf16(a0, bf0, acc, 0, 0, 0);
        acc = __builtin_amdgcn_mfma_f32_16x16x32_bf16(a1, bf1, acc, 0, 0, 0);
        float bv = b1v[j];
#pragma unroll
        for (int r = 0; r < 4; r++) {
            float hv = fmaxf(acc[r] + bv, 0.f);
            htile[(hrow0 + r) * HT_LD + j] = f2bf(hv);
        }
    }

    // GEMM2: OUT = relu(H) @ W2
    bf16x8v ha0 = *reinterpret_cast<const bf16x8v*>(&htile[arow * HT_LD + 0 * 32 + q * 8]);
    bf16x8v ha1 = *reinterpret_cast<const bf16x8v*>(&htile[arow * HT_LD + 1 * 32 + q * 8]);
    bf16x8v ha2 = *reinterpret_cast<const bf16x8v*>(&htile[arow * HT_LD + 2 * 32 + q * 8]);
    bf16x8v ha3 = *reinterpret_cast<const bf16x8v*>(&htile[arow * HT_LD + 3 * 32 + q * 8]);
#pragma unroll
    for (int dt = 0; dt < 4; dt++) {
        int d = dt * 16 + m;
        f32x4 acc = {0.f, 0.f, 0.f, 0.f};
        bf16x8v bw0 = *reinterpret_cast<const bf16x8v*>(&w2s[d * W2_LD + 0 * 32 + q * 8]);
        bf16x8v bw1 = *reinterpret_cast<const bf16x8v*>(&w2s[d * W2_LD + 1 * 32 + q * 8]);
        bf16x8v bw2 = *reinterpret_cast<const bf16x8v*>(&w2s[d * W2_LD + 2 * 32 + q * 8]);
        bf16x8v bw3 = *reinterpret_cast<const bf16x8v*>(&w2s[d * W2_LD + 3 * 32 + q * 8]);
        acc = __builtin_amdgcn_mfma_f32_16x16x32_bf16(ha0, bw0, acc, 0, 0, 0);
        acc = __builtin_amdgcn_mfma_f32_16x16x32_bf16(ha1, bw1, acc, 0, 0, 0);
        acc = __builtin_amdgcn_mfma_f32_16x16x32_bf16(ha2, bw2, acc, 0, 0, 0);
        acc = __builtin_amdgcn_mfma_f32_16x16x32_bf16(ha3, bw3, acc, 0, 0, 0);
        float bv = b2v[d];
#pragma unroll
        for (int r = 0; r < 4; r++) {
            int node = nb + hrow0 + r;
            if (node < N_NODES) out[(size_t)node * D_INF + d] = acc[r] + bv;
        }
    }
}

// ---------------------------------------------------------------------------
// Fallback (atomic scatter + convert) — only if ws_size is too small
// ---------------------------------------------------------------------------

__global__ void init_agg_kernel(const float* __restrict__ x, float* __restrict__ agg) {
    int i = blockIdx.x * blockDim.x + threadIdx.x;
    int n4 = N_NODES * D_INF / 4;
    if (i < n4) {
        reinterpret_cast<float4*>(agg)[i] = reinterpret_cast<const float4*>(x)[i];
    }
}

__global__ void scatter_kernel(const float* __restrict__ x,
                               const int* __restrict__ src,
                               const int* __restrict__ dst,
                               float* __restrict__ agg) {
    int tid = blockIdx.x * blockDim.x + threadIdx.x;
    int e = tid >> 6;
    int d = tid & 63;
    if (e < N_EDGES) {
        atomicAdd(&agg[(size_t)dst[e] * D_INF + d], x[(size_t)src[e] * D_INF + d]);
    }
}

__global__ void cvt_agg_kernel(const float* __restrict__ agg32, ushort* __restrict__ aggb) {
    int i = blockIdx.x * blockDim.x + threadIdx.x;
    if (i < N_NODES * D_INF) aggb[i] = f2bf(agg32[i]);
}

__global__ void prep_weights_only_kernel(const float* __restrict__ W1,
                                         const float* __restrict__ W2,
                                         ushort* __restrict__ w1tb,
                                         ushort* __restrict__ w2tb) {
    int i = blockIdx.x * blockDim.x + threadIdx.x;
    if (i < D_INF * D_HIDF) {
        int j = i >> 6, l = i & 63;
        w1tb[i] = f2bf(W1[l * D_HIDF + j]);
        int d = i >> 7, jj = i & 127;
        w2tb[i] = f2bf(W2[jj * D_INF + d]);
    }
}

// ---------------------------------------------------------------------------

extern "C" void kernel_launch(void* const* d_in, const int* in_sizes, int n_in,
                              void* d_out, int out_size, void* d_ws, size_t ws_size,
                              hipStream_t stream) {
    const float* x   = (const float*)d_in[0];
    const int* edge  = (const int*)d_in[1];   // [2, E]: src = edge, dst = edge + E
    const float* W1  = (const float*)d_in[2];
    const float* b1  = (const float*)d_in[3];
    const float* W2  = (const float*)d_in[4];
    const float* b2  = (const float*)d_in[5];
    float* out       = (float*)d_out;

    const int* src = edge;
    const int* dst = edge + N_EDGES;

    // Workspace layout:
    //   aggb  : N*64 bf16 (6.4 MB)
    //   w1tb  : 8192 bf16 ; w2tb : 8192 bf16
    //   xb    : N*64 bf16 (6.4 MB)
    //   cnt_g : 782 ints ; base_g : 782 ints ; gcursor : 782 ints
    //   binned: E uint (3.2 MB)
    //   agg32 (fallback only): N*64 f32 at xb position
    ushort* aggb   = (ushort*)d_ws;
    ushort* w1tb   = aggb + (size_t)N_NODES * D_INF;
    ushort* w2tb   = w1tb + D_INF * D_HIDF;
    ushort* xb     = w2tb + D_INF * D_HIDF;
    int* cnt_g     = (int*)(xb + (size_t)N_NODES * D_INF);
    int* base_g    = cnt_g + NBUCKET;
    int* gcursor   = base_g + NBUCKET;
    unsigned int* binned = (unsigned int*)(gcursor + NBUCKET);
    float* agg32   = (float*)(((uintptr_t)xb + 15) & ~(uintptr_t)15);

    size_t needed_full = (uintptr_t)(binned + N_EDGES) - (uintptr_t)d_ws;
    size_t needed_fb   = ((uintptr_t)agg32 + (size_t)N_NODES * D_INF * 4) - (uintptr_t)d_ws;

    if (ws_size >= needed_full) {
        int prep_total = CVT_N + PREP_N + NBUCKET;
        prep_kernel<<<(prep_total + 255) / 256, 256, 0, stream>>>(
            x, xb, W1, W2, w1tb, w2tb, cnt_g);
        hist_kernel<<<NCHUNK, 256, 0, stream>>>(dst, cnt_g);
        scan_kernel<<<1, 256, 0, stream>>>(cnt_g, base_g, gcursor);
        sortfill_kernel<<<NCHUNK, 256, 0, stream>>>(src, dst, gcursor, binned);
        tile_gather_kernel<<<NBUCKET, 256, 0, stream>>>(xb, binned, base_g, cnt_g, aggb);
    } else if (ws_size >= needed_fb) {
        prep_weights_only_kernel<<<(PREP_N + 255) / 256, 256, 0, stream>>>(W1, W2, w1tb, w2tb);
        int n4 = N_NODES * D_INF / 4;
        init_agg_kernel<<<(n4 + 255) / 256, 256, 0, stream>>>(x, agg32);
        int work = N_EDGES * D_INF;
        scatter_kernel<<<(work + 255) / 256, 256, 0, stream>>>(x, src, dst, agg32);
        cvt_agg_kernel<<<(N_NODES * D_INF + 255) / 256, 256, 0, stream>>>(agg32, aggb);
    }

    // MLP: 64-node tiles, 4 waves/block, bf16 MFMA
    mlp_mfma_kernel<<<(N_NODES + 63) / 64, 256, 0, stream>>>(aggb, w1tb, b1, w2tb, b2, out);
}

// Round 13
// 99.863 us; speedup vs baseline: 4.1447x; 4.1447x over previous
//
#include <hip/hip_runtime.h>

#define N_NODES 50000
#define N_EDGES 800000
#define D_INF 64
#define D_HIDF 128

#define NBUCKET ((N_NODES + 63) / 64)          // 782 buckets of 64 dst nodes
#define CHUNK 4096
#define NCHUNK ((N_EDGES + CHUNK - 1) / CHUNK) // 196 sort-fill blocks
#define MAXB 4096                               // nodesort LDS capacity (avg 1024)

typedef __attribute__((ext_vector_type(8))) short bf16x8v;
typedef __attribute__((ext_vector_type(4))) float f32x4;

__device__ __forceinline__ ushort f2bf(float f) {
    unsigned int u = __builtin_bit_cast(unsigned int, f);
    u += 0x7FFF + ((u >> 16) & 1);  // RNE
    return (ushort)(u >> 16);
}
__device__ __forceinline__ float bf2f(ushort u) {
    return __builtin_bit_cast(float, ((unsigned int)u) << 16);
}

// ---------------------------------------------------------------------------
// K1: fused prep — x->bf16, weight transpose->bf16, zero bucket counters.
// ---------------------------------------------------------------------------

#define CVT_N (N_NODES * D_INF / 8)   // 400000
#define PREP_N (D_INF * D_HIDF)       // 8192

__global__ void prep_kernel(const float* __restrict__ x, ushort* __restrict__ xb,
                            const float* __restrict__ W1, const float* __restrict__ W2,
                            ushort* __restrict__ w1tb, ushort* __restrict__ w2tb,
                            int* __restrict__ cnt_g) {
    int gid = blockIdx.x * blockDim.x + threadIdx.x;
    if (gid < CVT_N) {
        float4 a = reinterpret_cast<const float4*>(x)[gid * 2];
        float4 b = reinterpret_cast<const float4*>(x)[gid * 2 + 1];
        ushort o[8] = {f2bf(a.x), f2bf(a.y), f2bf(a.z), f2bf(a.w),
                       f2bf(b.x), f2bf(b.y), f2bf(b.z), f2bf(b.w)};
        *reinterpret_cast<ulonglong2*>(xb + gid * 8) = *reinterpret_cast<ulonglong2*>(o);
    } else if (gid < CVT_N + PREP_N) {
        int i = gid - CVT_N;
        int j = i >> 6, l = i & 63;
        w1tb[i] = f2bf(W1[l * D_HIDF + j]);
        int d = i >> 7, jj = i & 127;
        w2tb[i] = f2bf(W2[jj * D_INF + d]);
    } else if (gid < CVT_N + PREP_N + NBUCKET) {
        cnt_g[gid - CVT_N - PREP_N] = 0;
    }
}

// ---------------------------------------------------------------------------
// K2: per-block LDS histogram of dst buckets -> global cnt_g
// ---------------------------------------------------------------------------

__global__ void __launch_bounds__(256) hist_kernel(const int* __restrict__ dst,
                                                   int* __restrict__ cnt_g) {
    __shared__ int cnt[NBUCKET];
    int t = threadIdx.x;
    for (int i = t; i < NBUCKET; i += 256) cnt[i] = 0;
    __syncthreads();
    int base = blockIdx.x * CHUNK;
#pragma unroll
    for (int k = 0; k < CHUNK / 256; k++) {
        int e = base + k * 256 + t;
        if (e < N_EDGES) atomicAdd(&cnt[dst[e] >> 6], 1);
    }
    __syncthreads();
    for (int i = t; i < NBUCKET; i += 256) {
        int c = cnt[i];
        if (c) atomicAdd(&cnt_g[i], c);
    }
}

// ---------------------------------------------------------------------------
// K3: single-block exclusive scan of cnt_g[782] -> base_g, gcursor
// ---------------------------------------------------------------------------

__global__ void __launch_bounds__(256) scan_kernel(const int* __restrict__ cnt_g,
                                                   int* __restrict__ base_g,
                                                   int* __restrict__ gcursor) {
    __shared__ int wsum[4];
    int t = threadIdx.x;
    int lane = t & 63;
    int wv = t >> 6;
    int b0 = t * 4;
    int v[4];
    int s = 0;
#pragma unroll
    for (int i = 0; i < 4; i++) {
        v[i] = (b0 + i < NBUCKET) ? cnt_g[b0 + i] : 0;
        s += v[i];
    }
    int incl = s;
#pragma unroll
    for (int off = 1; off < 64; off <<= 1) {
        int u = __shfl_up(incl, off);
        if (lane >= off) incl += u;
    }
    if (lane == 63) wsum[wv] = incl;
    __syncthreads();
    if (t == 0) { wsum[1] += wsum[0]; wsum[2] += wsum[1]; wsum[3] += wsum[2]; }
    __syncthreads();
    int run = ((wv > 0) ? wsum[wv - 1] : 0) + (incl - s);
#pragma unroll
    for (int i = 0; i < 4; i++) {
        if (b0 + i < NBUCKET) {
            base_g[b0 + i] = run;
            gcursor[b0 + i] = run;
        }
        run += v[i];
    }
}

// ---------------------------------------------------------------------------
// K4: sort-fill. Each block counting-sorts its 4096-edge chunk by bucket in
// LDS, reserves contiguous global ranges, writes binned[] in contiguous runs.
// pack = (dst<<16)|src (both < 65536).
// ---------------------------------------------------------------------------

__global__ void __launch_bounds__(256) sortfill_kernel(const int* __restrict__ src,
                                                       const int* __restrict__ dst,
                                                       int* __restrict__ gcursor,
                                                       unsigned int* __restrict__ binned) {
    __shared__ int cnt[NBUCKET];
    __shared__ int off[NBUCKET];
    __shared__ int cur[NBUCKET];
    __shared__ int gbase[NBUCKET];
    __shared__ unsigned int buf[CHUNK];
    __shared__ int wsum[4];

    int t = threadIdx.x;
    int lane = t & 63;
    int wv = t >> 6;
    int base = blockIdx.x * CHUNK;
    int chunk_n = min(CHUNK, N_EDGES - base);

    for (int i = t; i < NBUCKET; i += 256) cnt[i] = 0;
    __syncthreads();

#pragma unroll
    for (int k = 0; k < CHUNK / 256; k++) {
        int e = base + k * 256 + t;
        if (e < N_EDGES) atomicAdd(&cnt[dst[e] >> 6], 1);
    }
    __syncthreads();

    {
        int b0 = t * 4;
        int v[4];
        int s = 0;
#pragma unroll
        for (int i = 0; i < 4; i++) {
            v[i] = (b0 + i < NBUCKET) ? cnt[b0 + i] : 0;
            s += v[i];
        }
        int incl = s;
#pragma unroll
        for (int o = 1; o < 64; o <<= 1) {
            int u = __shfl_up(incl, o);
            if (lane >= o) incl += u;
        }
        if (lane == 63) wsum[wv] = incl;
        __syncthreads();
        if (t == 0) { wsum[1] += wsum[0]; wsum[2] += wsum[1]; wsum[3] += wsum[2]; }
        __syncthreads();
        int run = ((wv > 0) ? wsum[wv - 1] : 0) + (incl - s);
#pragma unroll
        for (int i = 0; i < 4; i++) {
            int b = b0 + i;
            if (b < NBUCKET) {
                off[b] = run;
                cur[b] = run;
                if (v[i] > 0) gbase[b] = atomicAdd(&gcursor[b], v[i]);
            }
            run += v[i];
        }
    }
    __syncthreads();

#pragma unroll
    for (int k = 0; k < CHUNK / 256; k++) {
        int e = base + k * 256 + t;
        if (e < N_EDGES) {
            int d = dst[e];
            int s = src[e];
            int b = d >> 6;
            int r = atomicAdd(&cur[b], 1);
            buf[r] = ((unsigned int)d << 16) | (unsigned int)s;
        }
    }
    __syncthreads();

#pragma unroll
    for (int k = 0; k < CHUNK / 256; k++) {
        int slot = k * 256 + t;
        if (slot < chunk_n) {
            unsigned int pk = buf[slot];
            int b = pk >> 22;
            binned[gbase[b] + (slot - off[b])] = pk;
        }
    }
}

// ---------------------------------------------------------------------------
// K4.5: nodesort. One block per bucket: counting-sort the bucket's segment by
// node (6-bit) IN PLACE in binned; emit rowptr[node]. Oversized buckets
// (> MAXB, ~never) get sentinel rowptr = -(b+1) and stay bucket-sorted only.
// ---------------------------------------------------------------------------

__global__ void __launch_bounds__(256) nodesort_kernel(
    unsigned int* __restrict__ binned, const int* __restrict__ base_g,
    const int* __restrict__ cnt_g, int* __restrict__ rowptr)
{
    __shared__ unsigned int seg[MAXB];     // 16 KB
    __shared__ unsigned int sorted[MAXB];  // 16 KB
    __shared__ int c64[64];
    __shared__ int o64[64];
    int t = threadIdx.x;
    int b = blockIdx.x;
    int beg = base_g[b];
    int cnt = cnt_g[b];
    int nb = b * 64;
    int nvalid = min(64, N_NODES - nb);

    if (t < 64) c64[t] = 0;
    __syncthreads();

    if (cnt <= MAXB) {
        for (int i = t; i < cnt; i += 256) {
            unsigned int pk = binned[beg + i];
            seg[i] = pk;
            atomicAdd(&c64[(pk >> 16) & 63], 1);
        }
        __syncthreads();
        if (t < 64) {  // wave 0: exclusive scan of 64 counts
            int v = c64[t];
            int incl = v;
#pragma unroll
            for (int off = 1; off < 64; off <<= 1) {
                int u = __shfl_up(incl, off);
                if (t >= off) incl += u;
            }
            o64[t] = incl - v;
            if (t < nvalid) rowptr[nb + t] = beg + incl - v;
        }
        __syncthreads();
        for (int i = t; i < cnt; i += 256) {
            unsigned int pk = seg[i];
            int pos = atomicAdd(&o64[(pk >> 16) & 63], 1);
            sorted[pos] = pk;
        }
        __syncthreads();
        for (int i = t; i < cnt; i += 256) binned[beg + i] = sorted[i];
    } else {
        if (t < nvalid) rowptr[nb + t] = -(b + 1);  // sentinel: unsorted bucket
    }
    if (b == NBUCKET - 1 && t == 0) rowptr[N_NODES] = N_EDGES;
}

// ---------------------------------------------------------------------------
// K5: CSR gather. One wave per node (12500 blocks): contiguous edge segment,
// 8 independent bf16 row loads per iteration. No atomics, no chains.
// ---------------------------------------------------------------------------

__global__ void __launch_bounds__(256) gather_csr_kernel(
    const ushort* __restrict__ xb, const unsigned int* __restrict__ binned,
    const int* __restrict__ rowptr, const int* __restrict__ base_g,
    const int* __restrict__ cnt_g, ushort* __restrict__ aggb)
{
    int wid = (blockIdx.x * blockDim.x + threadIdx.x) >> 6;
    int lane = threadIdx.x & 63;
    if (wid >= N_NODES) return;

    float s0 = bf2f(xb[(size_t)wid * D_INF + lane]);
    float s1 = 0.f, s2 = 0.f, s3 = 0.f, s4 = 0.f, s5 = 0.f, s6 = 0.f, s7 = 0.f;

    int beg = rowptr[wid];
    if (beg >= 0) {
        int end = rowptr[wid + 1];
        if (end < 0) {  // next bucket unsorted: this node is last in its bucket
            int b = wid >> 6;
            end = base_g[b] + cnt_g[b];
        }
        int e = beg;
        for (; e + 7 < end; e += 8) {
            unsigned int p0 = binned[e + 0];
            unsigned int p1 = binned[e + 1];
            unsigned int p2 = binned[e + 2];
            unsigned int p3 = binned[e + 3];
            unsigned int p4 = binned[e + 4];
            unsigned int p5 = binned[e + 5];
            unsigned int p6 = binned[e + 6];
            unsigned int p7 = binned[e + 7];
            s0 += bf2f(xb[(size_t)(p0 & 0xFFFFu) * D_INF + lane]);
            s1 += bf2f(xb[(size_t)(p1 & 0xFFFFu) * D_INF + lane]);
            s2 += bf2f(xb[(size_t)(p2 & 0xFFFFu) * D_INF + lane]);
            s3 += bf2f(xb[(size_t)(p3 & 0xFFFFu) * D_INF + lane]);
            s4 += bf2f(xb[(size_t)(p4 & 0xFFFFu) * D_INF + lane]);
            s5 += bf2f(xb[(size_t)(p5 & 0xFFFFu) * D_INF + lane]);
            s6 += bf2f(xb[(size_t)(p6 & 0xFFFFu) * D_INF + lane]);
            s7 += bf2f(xb[(size_t)(p7 & 0xFFFFu) * D_INF + lane]);
        }
        for (; e + 3 < end; e += 4) {
            unsigned int p0 = binned[e + 0];
            unsigned int p1 = binned[e + 1];
            unsigned int p2 = binned[e + 2];
            unsigned int p3 = binned[e + 3];
            s0 += bf2f(xb[(size_t)(p0 & 0xFFFFu) * D_INF + lane]);
            s1 += bf2f(xb[(size_t)(p1 & 0xFFFFu) * D_INF + lane]);
            s2 += bf2f(xb[(size_t)(p2 & 0xFFFFu) * D_INF + lane]);
            s3 += bf2f(xb[(size_t)(p3 & 0xFFFFu) * D_INF + lane]);
        }
        for (; e < end; e++) {
            unsigned int p = binned[e];
            s0 += bf2f(xb[(size_t)(p & 0xFFFFu) * D_INF + lane]);
        }
    } else {  // unsorted bucket: scan whole segment, filter by dst
        int b = wid >> 6;
        int sbeg = base_g[b];
        int send = sbeg + cnt_g[b];
        for (int e = sbeg; e < send; e++) {
            unsigned int p = binned[e];
            if ((p >> 16) == (unsigned int)wid)
                s0 += bf2f(xb[(size_t)(p & 0xFFFFu) * D_INF + lane]);
        }
    }
    aggb[(size_t)wid * D_INF + lane] = f2bf(((s0 + s1) + (s2 + s3)) + ((s4 + s5) + (s6 + s7)));
}

// ---------------------------------------------------------------------------
// K6: MLP (MFMA), unchanged (proven).
// ---------------------------------------------------------------------------

#define AT_LD 72
#define W1_LD 72
#define HT_LD 136
#define W2_LD 136

__global__ void __launch_bounds__(256) mlp_mfma_kernel(
    const ushort* __restrict__ aggb, const ushort* __restrict__ w1tb,
    const float* __restrict__ b1v, const ushort* __restrict__ w2tb,
    const float* __restrict__ b2v, float* __restrict__ out)
{
    __shared__ __align__(16) ushort atile[64 * AT_LD];
    __shared__ __align__(16) ushort w1s[128 * W1_LD];
    __shared__ __align__(16) ushort w2s[64 * W2_LD];
    __shared__ __align__(16) ushort htile[64 * HT_LD];

    int tid = threadIdx.x;
    int lane = tid & 63;
    int wv = tid >> 6;
    int nb = blockIdx.x * 64;

#pragma unroll
    for (int c = 0; c < 2; c++) {
        int chunk = tid + c * 256;
        int row = chunk >> 3;
        int col = (chunk & 7) * 8;
        ulonglong2 v;
        v.x = 0; v.y = 0;
        if (nb + row < N_NODES)
            v = *reinterpret_cast<const ulonglong2*>(aggb + (size_t)(nb + row) * D_INF + col);
        *reinterpret_cast<ulonglong2*>(&atile[row * AT_LD + col]) = v;
    }
#pragma unroll
    for (int c = 0; c < 4; c++) {
        int chunk = tid + c * 256;
        int row = chunk >> 3;
        int col = (chunk & 7) * 8;
        *reinterpret_cast<ulonglong2*>(&w1s[row * W1_LD + col]) =
            *reinterpret_cast<const ulonglong2*>(w1tb + row * 64 + col);
    }
#pragma unroll
    for (int c = 0; c < 4; c++) {
        int chunk = tid + c * 256;
        int row = chunk >> 4;
        int col = (chunk & 15) * 8;
        *reinterpret_cast<ulonglong2*>(&w2s[row * W2_LD + col]) =
            *reinterpret_cast<const ulonglong2*>(w2tb + row * 128 + col);
    }
    __syncthreads();

    int q = lane >> 4;
    int m = lane & 15;
    int arow = wv * 16 + m;
    int hrow0 = wv * 16 + q * 4;

    bf16x8v a0 = *reinterpret_cast<const bf16x8v*>(&atile[arow * AT_LD + q * 8]);
    bf16x8v a1 = *reinterpret_cast<const bf16x8v*>(&atile[arow * AT_LD + 32 + q * 8]);
#pragma unroll
    for (int jt = 0; jt < 8; jt++) {
        int j = jt * 16 + m;
        bf16x8v bf0 = *reinterpret_cast<const bf16x8v*>(&w1s[j * W1_LD + q * 8]);
        bf16x8v bf1 = *reinterpret_cast<const bf16x8v*>(&w1s[j * W1_LD + 32 + q * 8]);
        f32x4 acc = {0.f, 0.f, 0.f, 0.f};
        acc = __builtin_amdgcn_mfma_f32_16x16x32_bf16(a0, bf0, acc, 0, 0, 0);
        acc = __builtin_amdgcn_mfma_f32_16x16x32_bf16(a1, bf1, acc, 0, 0, 0);
        float bv = b1v[j];
#pragma unroll
        for (int r = 0; r < 4; r++) {
            float hv = fmaxf(acc[r] + bv, 0.f);
            htile[(hrow0 + r) * HT_LD + j] = f2bf(hv);
        }
    }

    bf16x8v ha0 = *reinterpret_cast<const bf16x8v*>(&htile[arow * HT_LD + 0 * 32 + q * 8]);
    bf16x8v ha1 = *reinterpret_cast<const bf16x8v*>(&htile[arow * HT_LD + 1 * 32 + q * 8]);
    bf16x8v ha2 = *reinterpret_cast<const bf16x8v*>(&htile[arow * HT_LD + 2 * 32 + q * 8]);
    bf16x8v ha3 = *reinterpret_cast<const bf16x8v*>(&htile[arow * HT_LD + 3 * 32 + q * 8]);
#pragma unroll
    for (int dt = 0; dt < 4; dt++) {
        int d = dt * 16 + m;
        f32x4 acc = {0.f, 0.f, 0.f, 0.f};
        bf16x8v bw0 = *reinterpret_cast<const bf16x8v*>(&w2s[d * W2_LD + 0 * 32 + q * 8]);
        bf16x8v bw1 = *reinterpret_cast<const bf16x8v*>(&w2s[d * W2_LD + 1 * 32 + q * 8]);
        bf16x8v bw2 = *reinterpret_cast<const bf16x8v*>(&w2s[d * W2_LD + 2 * 32 + q * 8]);
        bf16x8v bw3 = *reinterpret_cast<const bf16x8v*>(&w2s[d * W2_LD + 3 * 32 + q * 8]);
        acc = __builtin_amdgcn_mfma_f32_16x16x32_bf16(ha0, bw0, acc, 0, 0, 0);
        acc = __builtin_amdgcn_mfma_f32_16x16x32_bf16(ha1, bw1, acc, 0, 0, 0);
        acc = __builtin_amdgcn_mfma_f32_16x16x32_bf16(ha2, bw2, acc, 0, 0, 0);
        acc = __builtin_amdgcn_mfma_f32_16x16x32_bf16(ha3, bw3, acc, 0, 0, 0);
        float bv = b2v[d];
#pragma unroll
        for (int r = 0; r < 4; r++) {
            int node = nb + hrow0 + r;
            if (node < N_NODES) out[(size_t)node * D_INF + d] = acc[r] + bv;
        }
    }
}

// ---------------------------------------------------------------------------
// Fallback (atomic scatter + convert) — only if ws_size is too small
// ---------------------------------------------------------------------------

__global__ void init_agg_kernel(const float* __restrict__ x, float* __restrict__ agg) {
    int i = blockIdx.x * blockDim.x + threadIdx.x;
    int n4 = N_NODES * D_INF / 4;
    if (i < n4) {
        reinterpret_cast<float4*>(agg)[i] = reinterpret_cast<const float4*>(x)[i];
    }
}

__global__ void scatter_kernel(const float* __restrict__ x,
                               const int* __restrict__ src,
                               const int* __restrict__ dst,
                               float* __restrict__ agg) {
    int tid = blockIdx.x * blockDim.x + threadIdx.x;
    int e = tid >> 6;
    int d = tid & 63;
    if (e < N_EDGES) {
        atomicAdd(&agg[(size_t)dst[e] * D_INF + d], x[(size_t)src[e] * D_INF + d]);
    }
}

__global__ void cvt_agg_kernel(const float* __restrict__ agg32, ushort* __restrict__ aggb) {
    int i = blockIdx.x * blockDim.x + threadIdx.x;
    if (i < N_NODES * D_INF) aggb[i] = f2bf(agg32[i]);
}

__global__ void prep_weights_only_kernel(const float* __restrict__ W1,
                                         const float* __restrict__ W2,
                                         ushort* __restrict__ w1tb,
                                         ushort* __restrict__ w2tb) {
    int i = blockIdx.x * blockDim.x + threadIdx.x;
    if (i < D_INF * D_HIDF) {
        int j = i >> 6, l = i & 63;
        w1tb[i] = f2bf(W1[l * D_HIDF + j]);
        int d = i >> 7, jj = i & 127;
        w2tb[i] = f2bf(W2[jj * D_INF + d]);
    }
}

// ---------------------------------------------------------------------------

extern "C" void kernel_launch(void* const* d_in, const int* in_sizes, int n_in,
                              void* d_out, int out_size, void* d_ws, size_t ws_size,
                              hipStream_t stream) {
    const float* x   = (const float*)d_in[0];
    const int* edge  = (const int*)d_in[1];   // [2, E]: src = edge, dst = edge + E
    const float* W1  = (const float*)d_in[2];
    const float* b1  = (const float*)d_in[3];
    const float* W2  = (const float*)d_in[4];
    const float* b2  = (const float*)d_in[5];
    float* out       = (float*)d_out;

    const int* src = edge;
    const int* dst = edge + N_EDGES;

    // Workspace layout (~16.24 MB; proven budget >= 16.63 MB):
    //   aggb : N*64 bf16 (6.4 MB)
    //   w1tb / w2tb : 8192 bf16 each
    //   xb   : N*64 bf16 (6.4 MB)
    //   cnt_g/base_g/gcursor : 782 ints each
    //   rowptr : N+1 ints (200 KB)
    //   binned : E uint (3.2 MB)
    //   agg32 (fallback only): N*64 f32 at xb position
    ushort* aggb   = (ushort*)d_ws;
    ushort* w1tb   = aggb + (size_t)N_NODES * D_INF;
    ushort* w2tb   = w1tb + D_INF * D_HIDF;
    ushort* xb     = w2tb + D_INF * D_HIDF;
    int* cnt_g     = (int*)(xb + (size_t)N_NODES * D_INF);
    int* base_g    = cnt_g + NBUCKET;
    int* gcursor   = base_g + NBUCKET;
    int* rowptr    = gcursor + NBUCKET;
    unsigned int* binned = (unsigned int*)(rowptr + N_NODES + 1);
    float* agg32   = (float*)(((uintptr_t)xb + 15) & ~(uintptr_t)15);

    size_t needed_full = (uintptr_t)(binned + N_EDGES) - (uintptr_t)d_ws;
    size_t needed_fb   = ((uintptr_t)agg32 + (size_t)N_NODES * D_INF * 4) - (uintptr_t)d_ws;

    if (ws_size >= needed_full) {
        int prep_total = CVT_N + PREP_N + NBUCKET;
        prep_kernel<<<(prep_total + 255) / 256, 256, 0, stream>>>(
            x, xb, W1, W2, w1tb, w2tb, cnt_g);
        hist_kernel<<<NCHUNK, 256, 0, stream>>>(dst, cnt_g);
        scan_kernel<<<1, 256, 0, stream>>>(cnt_g, base_g, gcursor);
        sortfill_kernel<<<NCHUNK, 256, 0, stream>>>(src, dst, gcursor, binned);
        nodesort_kernel<<<NBUCKET, 256, 0, stream>>>(binned, base_g, cnt_g, rowptr);
        int threads = N_NODES * 64;
        gather_csr_kernel<<<(threads + 255) / 256, 256, 0, stream>>>(
            xb, binned, rowptr, base_g, cnt_g, aggb);
    } else if (ws_size >= needed_fb) {
        prep_weights_only_kernel<<<(PREP_N + 255) / 256, 256, 0, stream>>>(W1, W2, w1tb, w2tb);
        int n4 = N_NODES * D_INF / 4;
        init_agg_kernel<<<(n4 + 255) / 256, 256, 0, stream>>>(x, agg32);
        int work = N_EDGES * D_INF;
        scatter_kernel<<<(work + 255) / 256, 256, 0, stream>>>(x, src, dst, agg32);
        cvt_agg_kernel<<<(N_NODES * D_INF + 255) / 256, 256, 0, stream>>>(agg32, aggb);
    }

    // MLP: 64-node tiles, 4 waves/block, bf16 MFMA
    mlp_mfma_kernel<<<(N_NODES + 63) / 64, 256, 0, stream>>>(aggb, w1tb, b1, w2tb, b2, out);
}

// Round 14
// 96.590 us; speedup vs baseline: 4.2852x; 1.0339x over previous
//
#include <hip/hip_runtime.h>

#define N_NODES 50000
#define N_EDGES 800000
#define D_INF 64
#define D_HIDF 128

#define NBUCKET ((N_NODES + 63) / 64)          // 782 buckets of 64 dst nodes
#define CHUNK 4096
#define NCHUNK ((N_EDGES + CHUNK - 1) / CHUNK) // 196 sort-fill blocks
#define MAXB 4096                               // mega LDS segment capacity

typedef __attribute__((ext_vector_type(8))) short bf16x8v;
typedef __attribute__((ext_vector_type(4))) float f32x4;

__device__ __forceinline__ ushort f2bf(float f) {
    unsigned int u = __builtin_bit_cast(unsigned int, f);
    u += 0x7FFF + ((u >> 16) & 1);  // RNE
    return (ushort)(u >> 16);
}
__device__ __forceinline__ float bf2f(ushort u) {
    return __builtin_bit_cast(float, ((unsigned int)u) << 16);
}

// ---------------------------------------------------------------------------
// K1: fused prep — x->bf16, weight transpose->bf16, zero bucket counters.
// ---------------------------------------------------------------------------

#define CVT_N (N_NODES * D_INF / 8)   // 400000
#define PREP_N (D_INF * D_HIDF)       // 8192

__global__ void prep_kernel(const float* __restrict__ x, ushort* __restrict__ xb,
                            const float* __restrict__ W1, const float* __restrict__ W2,
                            ushort* __restrict__ w1tb, ushort* __restrict__ w2tb,
                            int* __restrict__ cnt_g) {
    int gid = blockIdx.x * blockDim.x + threadIdx.x;
    if (gid < CVT_N) {
        float4 a = reinterpret_cast<const float4*>(x)[gid * 2];
        float4 b = reinterpret_cast<const float4*>(x)[gid * 2 + 1];
        ushort o[8] = {f2bf(a.x), f2bf(a.y), f2bf(a.z), f2bf(a.w),
                       f2bf(b.x), f2bf(b.y), f2bf(b.z), f2bf(b.w)};
        *reinterpret_cast<ulonglong2*>(xb + gid * 8) = *reinterpret_cast<ulonglong2*>(o);
    } else if (gid < CVT_N + PREP_N) {
        int i = gid - CVT_N;
        int j = i >> 6, l = i & 63;
        w1tb[i] = f2bf(W1[l * D_HIDF + j]);
        int d = i >> 7, jj = i & 127;
        w2tb[i] = f2bf(W2[jj * D_INF + d]);
    } else if (gid < CVT_N + PREP_N + NBUCKET) {
        cnt_g[gid - CVT_N - PREP_N] = 0;
    }
}

// ---------------------------------------------------------------------------
// K2: per-block LDS histogram of dst buckets -> global cnt_g
// ---------------------------------------------------------------------------

__global__ void __launch_bounds__(256) hist_kernel(const int* __restrict__ dst,
                                                   int* __restrict__ cnt_g) {
    __shared__ int cnt[NBUCKET];
    int t = threadIdx.x;
    for (int i = t; i < NBUCKET; i += 256) cnt[i] = 0;
    __syncthreads();
    int base = blockIdx.x * CHUNK;
#pragma unroll
    for (int k = 0; k < CHUNK / 256; k++) {
        int e = base + k * 256 + t;
        if (e < N_EDGES) atomicAdd(&cnt[dst[e] >> 6], 1);
    }
    __syncthreads();
    for (int i = t; i < NBUCKET; i += 256) {
        int c = cnt[i];
        if (c) atomicAdd(&cnt_g[i], c);
    }
}

// ---------------------------------------------------------------------------
// K3: single-block exclusive scan of cnt_g[782] -> base_g, gcursor
// ---------------------------------------------------------------------------

__global__ void __launch_bounds__(256) scan_kernel(const int* __restrict__ cnt_g,
                                                   int* __restrict__ base_g,
                                                   int* __restrict__ gcursor) {
    __shared__ int wsum[4];
    int t = threadIdx.x;
    int lane = t & 63;
    int wv = t >> 6;
    int b0 = t * 4;
    int v[4];
    int s = 0;
#pragma unroll
    for (int i = 0; i < 4; i++) {
        v[i] = (b0 + i < NBUCKET) ? cnt_g[b0 + i] : 0;
        s += v[i];
    }
    int incl = s;
#pragma unroll
    for (int off = 1; off < 64; off <<= 1) {
        int u = __shfl_up(incl, off);
        if (lane >= off) incl += u;
    }
    if (lane == 63) wsum[wv] = incl;
    __syncthreads();
    if (t == 0) { wsum[1] += wsum[0]; wsum[2] += wsum[1]; wsum[3] += wsum[2]; }
    __syncthreads();
    int run = ((wv > 0) ? wsum[wv - 1] : 0) + (incl - s);
#pragma unroll
    for (int i = 0; i < 4; i++) {
        if (b0 + i < NBUCKET) {
            base_g[b0 + i] = run;
            gcursor[b0 + i] = run;
        }
        run += v[i];
    }
}

// ---------------------------------------------------------------------------
// K4: sort-fill (unchanged, proven). pack = (dst<<16)|src.
// ---------------------------------------------------------------------------

__global__ void __launch_bounds__(256) sortfill_kernel(const int* __restrict__ src,
                                                       const int* __restrict__ dst,
                                                       int* __restrict__ gcursor,
                                                       unsigned int* __restrict__ binned) {
    __shared__ int cnt[NBUCKET];
    __shared__ int off[NBUCKET];
    __shared__ int cur[NBUCKET];
    __shared__ int gbase[NBUCKET];
    __shared__ unsigned int buf[CHUNK];
    __shared__ int wsum[4];

    int t = threadIdx.x;
    int lane = t & 63;
    int wv = t >> 6;
    int base = blockIdx.x * CHUNK;
    int chunk_n = min(CHUNK, N_EDGES - base);

    for (int i = t; i < NBUCKET; i += 256) cnt[i] = 0;
    __syncthreads();

#pragma unroll
    for (int k = 0; k < CHUNK / 256; k++) {
        int e = base + k * 256 + t;
        if (e < N_EDGES) atomicAdd(&cnt[dst[e] >> 6], 1);
    }
    __syncthreads();

    {
        int b0 = t * 4;
        int v[4];
        int s = 0;
#pragma unroll
        for (int i = 0; i < 4; i++) {
            v[i] = (b0 + i < NBUCKET) ? cnt[b0 + i] : 0;
            s += v[i];
        }
        int incl = s;
#pragma unroll
        for (int o = 1; o < 64; o <<= 1) {
            int u = __shfl_up(incl, o);
            if (lane >= o) incl += u;
        }
        if (lane == 63) wsum[wv] = incl;
        __syncthreads();
        if (t == 0) { wsum[1] += wsum[0]; wsum[2] += wsum[1]; wsum[3] += wsum[2]; }
        __syncthreads();
        int run = ((wv > 0) ? wsum[wv - 1] : 0) + (incl - s);
#pragma unroll
        for (int i = 0; i < 4; i++) {
            int b = b0 + i;
            if (b < NBUCKET) {
                off[b] = run;
                cur[b] = run;
                if (v[i] > 0) gbase[b] = atomicAdd(&gcursor[b], v[i]);
            }
            run += v[i];
        }
    }
    __syncthreads();

#pragma unroll
    for (int k = 0; k < CHUNK / 256; k++) {
        int e = base + k * 256 + t;
        if (e < N_EDGES) {
            int d = dst[e];
            int s = src[e];
            int b = d >> 6;
            int r = atomicAdd(&cur[b], 1);
            buf[r] = ((unsigned int)d << 16) | (unsigned int)s;
        }
    }
    __syncthreads();

#pragma unroll
    for (int k = 0; k < CHUNK / 256; k++) {
        int slot = k * 256 + t;
        if (slot < chunk_n) {
            unsigned int pk = buf[slot];
            int b = pk >> 22;
            binned[gbase[b] + (slot - off[b])] = pk;
        }
    }
}

// ---------------------------------------------------------------------------
// K5 (MEGA): one block per bucket, 1024 threads = 16 waves.
// Phase A: node-sort the bucket segment in LDS (no global write-back).
// Phase B: gather — wave w owns 4 nodes, 8-deep ILP xb-row loads -> bf16 atile.
// Phase C: MLP — 16 waves split the two GEMMs; weights direct from global/L2.
// ---------------------------------------------------------------------------

#define AT_LD 72
#define HT_LD 136

__global__ void __launch_bounds__(1024) mega_kernel(
    const ushort* __restrict__ xb, const unsigned int* __restrict__ binned,
    const int* __restrict__ base_g, const int* __restrict__ cnt_g,
    const ushort* __restrict__ w1tb, const float* __restrict__ b1v,
    const ushort* __restrict__ w2tb, const float* __restrict__ b2v,
    float* __restrict__ out)
{
    __shared__ unsigned int seg[MAXB];               // 16 KB
    __shared__ unsigned int sorted[MAXB];            // 16 KB
    __shared__ __align__(16) ushort atile[64 * AT_LD];  //  9.2 KB
    __shared__ __align__(16) ushort htile[64 * HT_LD];  // 17.4 KB
    __shared__ int c64[64];
    __shared__ int rb[65];
    __shared__ int o64[64];

    int t = threadIdx.x;
    int lane = t & 63;
    int wv = t >> 6;           // 0..15
    int b = blockIdx.x;
    int beg = base_g[b];
    int cnt = cnt_g[b];
    int nb = b * 64;
    int nvalid = min(64, N_NODES - nb);
    bool inlds = (cnt <= MAXB);   // block-uniform

    if (t < 64) c64[t] = 0;
    __syncthreads();

    // ---- Phase A: in-LDS counting sort by node ----
    if (inlds) {
        for (int i = t; i < cnt; i += 1024) {
            unsigned int pk = binned[beg + i];
            seg[i] = pk;
            atomicAdd(&c64[(pk >> 16) & 63], 1);
        }
        __syncthreads();
        if (t < 64) {
            int v = c64[t];
            int incl = v;
#pragma unroll
            for (int off = 1; off < 64; off <<= 1) {
                int u = __shfl_up(incl, off);
                if (t >= off) incl += u;
            }
            rb[t] = incl - v;
            o64[t] = incl - v;
            if (t == 63) rb[64] = incl;
        }
        __syncthreads();
        for (int i = t; i < cnt; i += 1024) {
            unsigned int pk = seg[i];
            int pos = atomicAdd(&o64[(pk >> 16) & 63], 1);
            sorted[pos] = pk;
        }
        __syncthreads();
    }

    // ---- Phase B: gather (wave w -> nodes 4w..4w+3, lane = feature) ----
#pragma unroll
    for (int k = 0; k < 4; k++) {
        int n = wv * 4 + k;
        if (n < nvalid) {
            float s0 = bf2f(xb[(size_t)(nb + n) * D_INF + lane]);
            float s1 = 0.f, s2 = 0.f, s3 = 0.f, s4 = 0.f, s5 = 0.f, s6 = 0.f, s7 = 0.f;
            if (inlds) {
                int e = rb[n];
                int end = rb[n + 1];
                for (; e + 7 < end; e += 8) {
                    unsigned int p0 = sorted[e + 0];
                    unsigned int p1 = sorted[e + 1];
                    unsigned int p2 = sorted[e + 2];
                    unsigned int p3 = sorted[e + 3];
                    unsigned int p4 = sorted[e + 4];
                    unsigned int p5 = sorted[e + 5];
                    unsigned int p6 = sorted[e + 6];
                    unsigned int p7 = sorted[e + 7];
                    s0 += bf2f(xb[(size_t)(p0 & 0xFFFFu) * D_INF + lane]);
                    s1 += bf2f(xb[(size_t)(p1 & 0xFFFFu) * D_INF + lane]);
                    s2 += bf2f(xb[(size_t)(p2 & 0xFFFFu) * D_INF + lane]);
                    s3 += bf2f(xb[(size_t)(p3 & 0xFFFFu) * D_INF + lane]);
                    s4 += bf2f(xb[(size_t)(p4 & 0xFFFFu) * D_INF + lane]);
                    s5 += bf2f(xb[(size_t)(p5 & 0xFFFFu) * D_INF + lane]);
                    s6 += bf2f(xb[(size_t)(p6 & 0xFFFFu) * D_INF + lane]);
                    s7 += bf2f(xb[(size_t)(p7 & 0xFFFFu) * D_INF + lane]);
                }
                for (; e + 3 < end; e += 4) {
                    unsigned int p0 = sorted[e + 0];
                    unsigned int p1 = sorted[e + 1];
                    unsigned int p2 = sorted[e + 2];
                    unsigned int p3 = sorted[e + 3];
                    s0 += bf2f(xb[(size_t)(p0 & 0xFFFFu) * D_INF + lane]);
                    s1 += bf2f(xb[(size_t)(p1 & 0xFFFFu) * D_INF + lane]);
                    s2 += bf2f(xb[(size_t)(p2 & 0xFFFFu) * D_INF + lane]);
                    s3 += bf2f(xb[(size_t)(p3 & 0xFFFFu) * D_INF + lane]);
                }
                for (; e < end; e++) {
                    unsigned int p = sorted[e];
                    s0 += bf2f(xb[(size_t)(p & 0xFFFFu) * D_INF + lane]);
                }
            } else {  // oversized bucket (~never): scan global segment, filter
                for (int e = beg; e < beg + cnt; e++) {
                    unsigned int p = binned[e];
                    if (((p >> 16) & 63u) == (unsigned int)n)
                        s0 += bf2f(xb[(size_t)(p & 0xFFFFu) * D_INF + lane]);
                }
            }
            atile[n * AT_LD + lane] =
                f2bf(((s0 + s1) + (s2 + s3)) + ((s4 + s5) + (s6 + s7)));
        } else if (n < 64) {
            atile[n * AT_LD + lane] = 0;
        }
    }
    __syncthreads();

    // ---- Phase C: MLP ----
    int q = lane >> 4;
    int m = lane & 15;
    int mt = wv & 3;          // M-tile 0..3
    int arow = mt * 16 + m;
    int hrow0 = mt * 16 + q * 4;

    // GEMM1: wave handles j-tiles {2*(wv>>2), 2*(wv>>2)+1}
    bf16x8v a0 = *reinterpret_cast<const bf16x8v*>(&atile[arow * AT_LD + q * 8]);
    bf16x8v a1 = *reinterpret_cast<const bf16x8v*>(&atile[arow * AT_LD + 32 + q * 8]);
    int jt0 = (wv >> 2) * 2;
#pragma unroll
    for (int jj = 0; jj < 2; jj++) {
        int j = (jt0 + jj) * 16 + m;
        bf16x8v bf0 = *reinterpret_cast<const bf16x8v*>(w1tb + j * D_INF + q * 8);
        bf16x8v bf1 = *reinterpret_cast<const bf16x8v*>(w1tb + j * D_INF + 32 + q * 8);
        f32x4 acc = {0.f, 0.f, 0.f, 0.f};
        acc = __builtin_amdgcn_mfma_f32_16x16x32_bf16(a0, bf0, acc, 0, 0, 0);
        acc = __builtin_amdgcn_mfma_f32_16x16x32_bf16(a1, bf1, acc, 0, 0, 0);
        float bv = b1v[j];
#pragma unroll
        for (int r = 0; r < 4; r++) {
            float hv = fmaxf(acc[r] + bv, 0.f);
            htile[(hrow0 + r) * HT_LD + j] = f2bf(hv);
        }
    }
    __syncthreads();

    // GEMM2: wave handles d-tile (wv>>2) for its M-tile
    bf16x8v ha0 = *reinterpret_cast<const bf16x8v*>(&htile[arow * HT_LD + 0 * 32 + q * 8]);
    bf16x8v ha1 = *reinterpret_cast<const bf16x8v*>(&htile[arow * HT_LD + 1 * 32 + q * 8]);
    bf16x8v ha2 = *reinterpret_cast<const bf16x8v*>(&htile[arow * HT_LD + 2 * 32 + q * 8]);
    bf16x8v ha3 = *reinterpret_cast<const bf16x8v*>(&htile[arow * HT_LD + 3 * 32 + q * 8]);
    {
        int d = (wv >> 2) * 16 + m;
        bf16x8v bw0 = *reinterpret_cast<const bf16x8v*>(w2tb + d * D_HIDF + 0 * 32 + q * 8);
        bf16x8v bw1 = *reinterpret_cast<const bf16x8v*>(w2tb + d * D_HIDF + 1 * 32 + q * 8);
        bf16x8v bw2 = *reinterpret_cast<const bf16x8v*>(w2tb + d * D_HIDF + 2 * 32 + q * 8);
        bf16x8v bw3 = *reinterpret_cast<const bf16x8v*>(w2tb + d * D_HIDF + 3 * 32 + q * 8);
        f32x4 acc = {0.f, 0.f, 0.f, 0.f};
        acc = __builtin_amdgcn_mfma_f32_16x16x32_bf16(ha0, bw0, acc, 0, 0, 0);
        acc = __builtin_amdgcn_mfma_f32_16x16x32_bf16(ha1, bw1, acc, 0, 0, 0);
        acc = __builtin_amdgcn_mfma_f32_16x16x32_bf16(ha2, bw2, acc, 0, 0, 0);
        acc = __builtin_amdgcn_mfma_f32_16x16x32_bf16(ha3, bw3, acc, 0, 0, 0);
        float bv = b2v[d];
#pragma unroll
        for (int r = 0; r < 4; r++) {
            int node = nb + hrow0 + r;
            if (node < N_NODES) out[(size_t)node * D_INF + d] = acc[r] + bv;
        }
    }
}

// ---------------------------------------------------------------------------
// Fallback path (ws too small): atomic scatter + standalone MLP (proven r8).
// ---------------------------------------------------------------------------

#define W1_LD 72
#define W2_LD 136

__global__ void __launch_bounds__(256) mlp_mfma_kernel(
    const ushort* __restrict__ aggb, const ushort* __restrict__ w1tb,
    const float* __restrict__ b1v, const ushort* __restrict__ w2tb,
    const float* __restrict__ b2v, float* __restrict__ out)
{
    __shared__ __align__(16) ushort atile[64 * AT_LD];
    __shared__ __align__(16) ushort w1s[128 * W1_LD];
    __shared__ __align__(16) ushort w2s[64 * W2_LD];
    __shared__ __align__(16) ushort htile[64 * HT_LD];

    int tid = threadIdx.x;
    int lane = tid & 63;
    int wv = tid >> 6;
    int nb = blockIdx.x * 64;

#pragma unroll
    for (int c = 0; c < 2; c++) {
        int chunk = tid + c * 256;
        int row = chunk >> 3;
        int col = (chunk & 7) * 8;
        ulonglong2 v;
        v.x = 0; v.y = 0;
        if (nb + row < N_NODES)
            v = *reinterpret_cast<const ulonglong2*>(aggb + (size_t)(nb + row) * D_INF + col);
        *reinterpret_cast<ulonglong2*>(&atile[row * AT_LD + col]) = v;
    }
#pragma unroll
    for (int c = 0; c < 4; c++) {
        int chunk = tid + c * 256;
        int row = chunk >> 3;
        int col = (chunk & 7) * 8;
        *reinterpret_cast<ulonglong2*>(&w1s[row * W1_LD + col]) =
            *reinterpret_cast<const ulonglong2*>(w1tb + row * 64 + col);
    }
#pragma unroll
    for (int c = 0; c < 4; c++) {
        int chunk = tid + c * 256;
        int row = chunk >> 4;
        int col = (chunk & 15) * 8;
        *reinterpret_cast<ulonglong2*>(&w2s[row * W2_LD + col]) =
            *reinterpret_cast<const ulonglong2*>(w2tb + row * 128 + col);
    }
    __syncthreads();

    int q = lane >> 4;
    int m = lane & 15;
    int arow = wv * 16 + m;
    int hrow0 = wv * 16 + q * 4;

    bf16x8v a0 = *reinterpret_cast<const bf16x8v*>(&atile[arow * AT_LD + q * 8]);
    bf16x8v a1 = *reinterpret_cast<const bf16x8v*>(&atile[arow * AT_LD + 32 + q * 8]);
#pragma unroll
    for (int jt = 0; jt < 8; jt++) {
        int j = jt * 16 + m;
        bf16x8v bf0 = *reinterpret_cast<const bf16x8v*>(&w1s[j * W1_LD + q * 8]);
        bf16x8v bf1 = *reinterpret_cast<const bf16x8v*>(&w1s[j * W1_LD + 32 + q * 8]);
        f32x4 acc = {0.f, 0.f, 0.f, 0.f};
        acc = __builtin_amdgcn_mfma_f32_16x16x32_bf16(a0, bf0, acc, 0, 0, 0);
        acc = __builtin_amdgcn_mfma_f32_16x16x32_bf16(a1, bf1, acc, 0, 0, 0);
        float bv = b1v[j];
#pragma unroll
        for (int r = 0; r < 4; r++) {
            float hv = fmaxf(acc[r] + bv, 0.f);
            htile[(hrow0 + r) * HT_LD + j] = f2bf(hv);
        }
    }

    bf16x8v ha0 = *reinterpret_cast<const bf16x8v*>(&htile[arow * HT_LD + 0 * 32 + q * 8]);
    bf16x8v ha1 = *reinterpret_cast<const bf16x8v*>(&htile[arow * HT_LD + 1 * 32 + q * 8]);
    bf16x8v ha2 = *reinterpret_cast<const bf16x8v*>(&htile[arow * HT_LD + 2 * 32 + q * 8]);
    bf16x8v ha3 = *reinterpret_cast<const bf16x8v*>(&htile[arow * HT_LD + 3 * 32 + q * 8]);
#pragma unroll
    for (int dt = 0; dt < 4; dt++) {
        int d = dt * 16 + m;
        f32x4 acc = {0.f, 0.f, 0.f, 0.f};
        bf16x8v bw0 = *reinterpret_cast<const bf16x8v*>(&w2s[d * W2_LD + 0 * 32 + q * 8]);
        bf16x8v bw1 = *reinterpret_cast<const bf16x8v*>(&w2s[d * W2_LD + 1 * 32 + q * 8]);
        bf16x8v bw2 = *reinterpret_cast<const bf16x8v*>(&w2s[d * W2_LD + 2 * 32 + q * 8]);
        bf16x8v bw3 = *reinterpret_cast<const bf16x8v*>(&w2s[d * W2_LD + 3 * 32 + q * 8]);
        acc = __builtin_amdgcn_mfma_f32_16x16x32_bf16(ha0, bw0, acc, 0, 0, 0);
        acc = __builtin_amdgcn_mfma_f32_16x16x32_bf16(ha1, bw1, acc, 0, 0, 0);
        acc = __builtin_amdgcn_mfma_f32_16x16x32_bf16(ha2, bw2, acc, 0, 0, 0);
        acc = __builtin_amdgcn_mfma_f32_16x16x32_bf16(ha3, bw3, acc, 0, 0, 0);
        float bv = b2v[d];
#pragma unroll
        for (int r = 0; r < 4; r++) {
            int node = nb + hrow0 + r;
            if (node < N_NODES) out[(size_t)node * D_INF + d] = acc[r] + bv;
        }
    }
}

__global__ void init_agg_kernel(const float* __restrict__ x, float* __restrict__ agg) {
    int i = blockIdx.x * blockDim.x + threadIdx.x;
    int n4 = N_NODES * D_INF / 4;
    if (i < n4) {
        reinterpret_cast<float4*>(agg)[i] = reinterpret_cast<const float4*>(x)[i];
    }
}

__global__ void scatter_kernel(const float* __restrict__ x,
                               const int* __restrict__ src,
                               const int* __restrict__ dst,
                               float* __restrict__ agg) {
    int tid = blockIdx.x * blockDim.x + threadIdx.x;
    int e = tid >> 6;
    int d = tid & 63;
    if (e < N_EDGES) {
        atomicAdd(&agg[(size_t)dst[e] * D_INF + d], x[(size_t)src[e] * D_INF + d]);
    }
}

__global__ void cvt_agg_kernel(const float* __restrict__ agg32, ushort* __restrict__ aggb) {
    int i = blockIdx.x * blockDim.x + threadIdx.x;
    if (i < N_NODES * D_INF) aggb[i] = f2bf(agg32[i]);
}

__global__ void prep_weights_only_kernel(const float* __restrict__ W1,
                                         const float* __restrict__ W2,
                                         ushort* __restrict__ w1tb,
                                         ushort* __restrict__ w2tb) {
    int i = blockIdx.x * blockDim.x + threadIdx.x;
    if (i < D_INF * D_HIDF) {
        int j = i >> 6, l = i & 63;
        w1tb[i] = f2bf(W1[l * D_HIDF + j]);
        int d = i >> 7, jj = i & 127;
        w2tb[i] = f2bf(W2[jj * D_INF + d]);
    }
}

// ---------------------------------------------------------------------------

extern "C" void kernel_launch(void* const* d_in, const int* in_sizes, int n_in,
                              void* d_out, int out_size, void* d_ws, size_t ws_size,
                              hipStream_t stream) {
    const float* x   = (const float*)d_in[0];
    const int* edge  = (const int*)d_in[1];   // [2, E]: src = edge, dst = edge + E
    const float* W1  = (const float*)d_in[2];
    const float* b1  = (const float*)d_in[3];
    const float* W2  = (const float*)d_in[4];
    const float* b2  = (const float*)d_in[5];
    float* out       = (float*)d_out;

    const int* src = edge;
    const int* dst = edge + N_EDGES;

    // Workspace layout (fast path ~16.2 MB; proven budget >= 16.63 MB):
    //   aggb : N*64 bf16 (6.4 MB)  [fallback only in fast path era, kept for tiers]
    //   w1tb / w2tb : 8192 bf16 each
    //   xb   : N*64 bf16 (6.4 MB)
    //   cnt_g/base_g/gcursor : 782 ints each
    //   binned : E uint (3.2 MB)
    //   agg32 (fallback only): N*64 f32 at xb position
    ushort* aggb   = (ushort*)d_ws;
    ushort* w1tb   = aggb + (size_t)N_NODES * D_INF;
    ushort* w2tb   = w1tb + D_INF * D_HIDF;
    ushort* xb     = w2tb + D_INF * D_HIDF;
    int* cnt_g     = (int*)(xb + (size_t)N_NODES * D_INF);
    int* base_g    = cnt_g + NBUCKET;
    int* gcursor   = base_g + NBUCKET;
    unsigned int* binned = (unsigned int*)(gcursor + NBUCKET);
    float* agg32   = (float*)(((uintptr_t)xb + 15) & ~(uintptr_t)15);

    size_t needed_full = (uintptr_t)(binned + N_EDGES) - (uintptr_t)d_ws;
    size_t needed_fb   = ((uintptr_t)agg32 + (size_t)N_NODES * D_INF * 4) - (uintptr_t)d_ws;

    if (ws_size >= needed_full) {
        int prep_total = CVT_N + PREP_N + NBUCKET;
        prep_kernel<<<(prep_total + 255) / 256, 256, 0, stream>>>(
            x, xb, W1, W2, w1tb, w2tb, cnt_g);
        hist_kernel<<<NCHUNK, 256, 0, stream>>>(dst, cnt_g);
        scan_kernel<<<1, 256, 0, stream>>>(cnt_g, base_g, gcursor);
        sortfill_kernel<<<NCHUNK, 256, 0, stream>>>(src, dst, gcursor, binned);
        mega_kernel<<<NBUCKET, 1024, 0, stream>>>(
            xb, binned, base_g, cnt_g, w1tb, b1, w2tb, b2, out);
    } else if (ws_size >= needed_fb) {
        prep_weights_only_kernel<<<(PREP_N + 255) / 256, 256, 0, stream>>>(W1, W2, w1tb, w2tb);
        int n4 = N_NODES * D_INF / 4;
        init_agg_kernel<<<(n4 + 255) / 256, 256, 0, stream>>>(x, agg32);
        int work = N_EDGES * D_INF;
        scatter_kernel<<<(work + 255) / 256, 256, 0, stream>>>(x, src, dst, agg32);
        cvt_agg_kernel<<<(N_NODES * D_INF + 255) / 256, 256, 0, stream>>>(agg32, aggb);
        mlp_mfma_kernel<<<(N_NODES + 63) / 64, 256, 0, stream>>>(aggb, w1tb, b1, w2tb, b2, out);
    }
}

// Round 15
// 79.834 us; speedup vs baseline: 5.1845x; 1.2099x over previous
//
#include <hip/hip_runtime.h>

#define N_NODES 50000
#define N_EDGES 800000
#define D_INF 64
#define D_HIDF 128

#define NBUCKET ((N_NODES + 63) / 64)          // 782 buckets of 64 dst nodes
#define CHUNK 4096
#define NCHUNK ((N_EDGES + CHUNK - 1) / CHUNK) // 196 sort-fill blocks
#define CAP 4096                               // per-bucket binned capacity (avg 1024)

typedef __attribute__((ext_vector_type(8))) short bf16x8v;
typedef __attribute__((ext_vector_type(4))) float f32x4;

__device__ __forceinline__ ushort f2bf(float f) {
    unsigned int u = __builtin_bit_cast(unsigned int, f);
    u += 0x7FFF + ((u >> 16) & 1);  // RNE
    return (ushort)(u >> 16);
}
__device__ __forceinline__ float bf2f(ushort u) {
    return __builtin_bit_cast(float, ((unsigned int)u) << 16);
}

// ---------------------------------------------------------------------------
// K1: fused prep — x->bf16, weight transpose->bf16, gcursor[b] = b*CAP.
// ---------------------------------------------------------------------------

#define CVT_N (N_NODES * D_INF / 8)   // 400000
#define PREP_N (D_INF * D_HIDF)       // 8192

__global__ void prep_kernel(const float* __restrict__ x, ushort* __restrict__ xb,
                            const float* __restrict__ W1, const float* __restrict__ W2,
                            ushort* __restrict__ w1tb, ushort* __restrict__ w2tb,
                            int* __restrict__ gcursor) {
    int gid = blockIdx.x * blockDim.x + threadIdx.x;
    if (gid < CVT_N) {
        float4 a = reinterpret_cast<const float4*>(x)[gid * 2];
        float4 b = reinterpret_cast<const float4*>(x)[gid * 2 + 1];
        ushort o[8] = {f2bf(a.x), f2bf(a.y), f2bf(a.z), f2bf(a.w),
                       f2bf(b.x), f2bf(b.y), f2bf(b.z), f2bf(b.w)};
        *reinterpret_cast<ulonglong2*>(xb + gid * 8) = *reinterpret_cast<ulonglong2*>(o);
    } else if (gid < CVT_N + PREP_N) {
        int i = gid - CVT_N;
        int j = i >> 6, l = i & 63;
        w1tb[i] = f2bf(W1[l * D_HIDF + j]);
        int d = i >> 7, jj = i & 127;
        w2tb[i] = f2bf(W2[jj * D_INF + d]);
    } else if (gid < CVT_N + PREP_N + NBUCKET) {
        int b = gid - CVT_N - PREP_N;
        gcursor[b] = b * CAP;
    }
}

// ---------------------------------------------------------------------------
// K2: sort-fill into capacity-partitioned binned[]. Each block counting-sorts
// its 4096-edge chunk by bucket in LDS, reserves contiguous ranges from
// gcursor (base b*CAP), writes contiguous runs. pack = (dst<<16)|src.
// ---------------------------------------------------------------------------

__global__ void __launch_bounds__(256) sortfill_kernel(const int* __restrict__ src,
                                                       const int* __restrict__ dst,
                                                       int* __restrict__ gcursor,
                                                       unsigned int* __restrict__ binned) {
    __shared__ int cnt[NBUCKET];
    __shared__ int off[NBUCKET];
    __shared__ int cur[NBUCKET];
    __shared__ int gbase[NBUCKET];
    __shared__ unsigned int buf[CHUNK];
    __shared__ int wsum[4];

    int t = threadIdx.x;
    int lane = t & 63;
    int wv = t >> 6;
    int base = blockIdx.x * CHUNK;
    int chunk_n = min(CHUNK, N_EDGES - base);

    for (int i = t; i < NBUCKET; i += 256) cnt[i] = 0;
    __syncthreads();

    // pass 1: local count
#pragma unroll
    for (int k = 0; k < CHUNK / 256; k++) {
        int e = base + k * 256 + t;
        if (e < N_EDGES) atomicAdd(&cnt[dst[e] >> 6], 1);
    }
    __syncthreads();

    // local scan + global reservation from gcursor (init'd to b*CAP)
    {
        int b0 = t * 4;
        int v[4];
        int s = 0;
#pragma unroll
        for (int i = 0; i < 4; i++) {
            v[i] = (b0 + i < NBUCKET) ? cnt[b0 + i] : 0;
            s += v[i];
        }
        int incl = s;
#pragma unroll
        for (int o = 1; o < 64; o <<= 1) {
            int u = __shfl_up(incl, o);
            if (lane >= o) incl += u;
        }
        if (lane == 63) wsum[wv] = incl;
        __syncthreads();
        if (t == 0) { wsum[1] += wsum[0]; wsum[2] += wsum[1]; wsum[3] += wsum[2]; }
        __syncthreads();
        int run = ((wv > 0) ? wsum[wv - 1] : 0) + (incl - s);
#pragma unroll
        for (int i = 0; i < 4; i++) {
            int b = b0 + i;
            if (b < NBUCKET) {
                off[b] = run;
                cur[b] = run;
                if (v[i] > 0) gbase[b] = atomicAdd(&gcursor[b], v[i]);
            }
            run += v[i];
        }
    }
    __syncthreads();

    // pass 2: place into LDS buffer sorted by bucket
#pragma unroll
    for (int k = 0; k < CHUNK / 256; k++) {
        int e = base + k * 256 + t;
        if (e < N_EDGES) {
            int d = dst[e];
            int s = src[e];
            int b = d >> 6;
            int r = atomicAdd(&cur[b], 1);
            buf[r] = ((unsigned int)d << 16) | (unsigned int)s;
        }
    }
    __syncthreads();

    // pass 3: contiguous-run writeout (capacity-guarded)
#pragma unroll
    for (int k = 0; k < CHUNK / 256; k++) {
        int slot = k * 256 + t;
        if (slot < chunk_n) {
            unsigned int pk = buf[slot];
            int b = pk >> 22;
            int idx = gbase[b] + (slot - off[b]);
            if (idx < (b + 1) * CAP) binned[idx] = pk;
        }
    }
}

// ---------------------------------------------------------------------------
// K3 (MEGA): one block per bucket, 1024 threads = 16 waves.
// Phase A: node-sort the bucket segment in LDS.
// Phase B: gather — 2 edges per dword load (half-wave per edge), 8-edge unroll.
// Phase C: MLP — 16 waves split both GEMMs; weights direct from global/L2.
// ---------------------------------------------------------------------------

#define AT_LD 72
#define HT_LD 136

__global__ void __launch_bounds__(1024) mega_kernel(
    const ushort* __restrict__ xb, const unsigned int* __restrict__ binned,
    const int* __restrict__ gcursor,
    const ushort* __restrict__ w1tb, const float* __restrict__ b1v,
    const ushort* __restrict__ w2tb, const float* __restrict__ b2v,
    float* __restrict__ out)
{
    __shared__ unsigned int seg[CAP];                   // 16 KB
    __shared__ unsigned int sorted[CAP];                // 16 KB
    __shared__ __align__(16) ushort atile[64 * AT_LD];  //  9.2 KB
    __shared__ __align__(16) ushort htile[64 * HT_LD];  // 17.4 KB
    __shared__ int c64[64];
    __shared__ int rb[65];
    __shared__ int o64[64];

    int t = threadIdx.x;
    int lane = t & 63;
    int wv = t >> 6;           // 0..15
    int b = blockIdx.x;
    int beg = b * CAP;
    int cnt = min(gcursor[b] - beg, CAP);
    int nb = b * 64;
    int nvalid = min(64, N_NODES - nb);

    if (t < 64) c64[t] = 0;
    __syncthreads();

    // ---- Phase A: in-LDS counting sort by node ----
    for (int i = t; i < cnt; i += 1024) {
        unsigned int pk = binned[beg + i];
        seg[i] = pk;
        atomicAdd(&c64[(pk >> 16) & 63], 1);
    }
    __syncthreads();
    if (t < 64) {
        int v = c64[t];
        int incl = v;
#pragma unroll
        for (int off = 1; off < 64; off <<= 1) {
            int u = __shfl_up(incl, off);
            if (t >= off) incl += u;
        }
        rb[t] = incl - v;
        o64[t] = incl - v;
        if (t == 63) rb[64] = incl;
    }
    __syncthreads();
    for (int i = t; i < cnt; i += 1024) {
        unsigned int pk = seg[i];
        int pos = atomicAdd(&o64[(pk >> 16) & 63], 1);
        sorted[pos] = pk;
    }
    __syncthreads();

    // ---- Phase B: gather (wave w -> nodes 4w..4w+3) ----
    // Half-wave h handles edge e+h; lane covers feature pair f2 via dword load.
    int h = lane >> 5;        // 0..1
    int f2 = lane & 31;       // feature pair index
#pragma unroll
    for (int k = 0; k < 4; k++) {
        int n = wv * 4 + k;
        if (n < nvalid) {
            float a0 = 0.f, a1 = 0.f;
            float b0f = 0.f, b1f = 0.f, c0f = 0.f, c1f = 0.f, d0f = 0.f, d1f = 0.f;
            int e = rb[n];
            int end = rb[n + 1];
            for (; e + 7 < end; e += 8) {
                unsigned int p0 = sorted[e + 0 + h];
                unsigned int p1 = sorted[e + 2 + h];
                unsigned int p2 = sorted[e + 4 + h];
                unsigned int p3 = sorted[e + 6 + h];
                unsigned int v0 = *reinterpret_cast<const unsigned int*>(
                    &xb[(size_t)(p0 & 0xFFFFu) * D_INF + f2 * 2]);
                unsigned int v1 = *reinterpret_cast<const unsigned int*>(
                    &xb[(size_t)(p1 & 0xFFFFu) * D_INF + f2 * 2]);
                unsigned int v2 = *reinterpret_cast<const unsigned int*>(
                    &xb[(size_t)(p2 & 0xFFFFu) * D_INF + f2 * 2]);
                unsigned int v3 = *reinterpret_cast<const unsigned int*>(
                    &xb[(size_t)(p3 & 0xFFFFu) * D_INF + f2 * 2]);
                a0 += bf2f((ushort)(v0 & 0xFFFFu));
                a1 += bf2f((ushort)(v0 >> 16));
                b0f += bf2f((ushort)(v1 & 0xFFFFu));
                b1f += bf2f((ushort)(v1 >> 16));
                c0f += bf2f((ushort)(v2 & 0xFFFFu));
                c1f += bf2f((ushort)(v2 >> 16));
                d0f += bf2f((ushort)(v3 & 0xFFFFu));
                d1f += bf2f((ushort)(v3 >> 16));
            }
            for (; e + 1 < end; e += 2) {
                unsigned int p = sorted[e + h];
                unsigned int v = *reinterpret_cast<const unsigned int*>(
                    &xb[(size_t)(p & 0xFFFFu) * D_INF + f2 * 2]);
                a0 += bf2f((ushort)(v & 0xFFFFu));
                a1 += bf2f((ushort)(v >> 16));
            }
            if (e < end && h == 0) {  // odd tail: half 0 only
                unsigned int p = sorted[e];
                unsigned int v = *reinterpret_cast<const unsigned int*>(
                    &xb[(size_t)(p & 0xFFFFu) * D_INF + f2 * 2]);
                a0 += bf2f((ushort)(v & 0xFFFFu));
                a1 += bf2f((ushort)(v >> 16));
            }
            a0 += (b0f + c0f) + d0f;
            a1 += (b1f + c1f) + d1f;
            // merge halves
            a0 += __shfl_xor(a0, 32);
            a1 += __shfl_xor(a1, 32);
            if (h == 0) {  // self term + write
                unsigned int v = *reinterpret_cast<const unsigned int*>(
                    &xb[(size_t)(nb + n) * D_INF + f2 * 2]);
                a0 += bf2f((ushort)(v & 0xFFFFu));
                a1 += bf2f((ushort)(v >> 16));
                unsigned int packed = (unsigned int)f2bf(a0) | ((unsigned int)f2bf(a1) << 16);
                *reinterpret_cast<unsigned int*>(&atile[n * AT_LD + f2 * 2]) = packed;
            }
        } else if (n < 64 && h == 0) {
            *reinterpret_cast<unsigned int*>(&atile[n * AT_LD + f2 * 2]) = 0u;
        }
    }
    __syncthreads();

    // ---- Phase C: MLP ----
    int q = lane >> 4;
    int m = lane & 15;
    int mt = wv & 3;          // M-tile 0..3
    int arow = mt * 16 + m;
    int hrow0 = mt * 16 + q * 4;

    bf16x8v a0v = *reinterpret_cast<const bf16x8v*>(&atile[arow * AT_LD + q * 8]);
    bf16x8v a1v = *reinterpret_cast<const bf16x8v*>(&atile[arow * AT_LD + 32 + q * 8]);
    int jt0 = (wv >> 2) * 2;
#pragma unroll
    for (int jj = 0; jj < 2; jj++) {
        int j = (jt0 + jj) * 16 + m;
        bf16x8v bf0 = *reinterpret_cast<const bf16x8v*>(w1tb + j * D_INF + q * 8);
        bf16x8v bf1 = *reinterpret_cast<const bf16x8v*>(w1tb + j * D_INF + 32 + q * 8);
        f32x4 acc = {0.f, 0.f, 0.f, 0.f};
        acc = __builtin_amdgcn_mfma_f32_16x16x32_bf16(a0v, bf0, acc, 0, 0, 0);
        acc = __builtin_amdgcn_mfma_f32_16x16x32_bf16(a1v, bf1, acc, 0, 0, 0);
        float bv = b1v[j];
#pragma unroll
        for (int r = 0; r < 4; r++) {
            float hv = fmaxf(acc[r] + bv, 0.f);
            htile[(hrow0 + r) * HT_LD + j] = f2bf(hv);
        }
    }
    __syncthreads();

    bf16x8v ha0 = *reinterpret_cast<const bf16x8v*>(&htile[arow * HT_LD + 0 * 32 + q * 8]);
    bf16x8v ha1 = *reinterpret_cast<const bf16x8v*>(&htile[arow * HT_LD + 1 * 32 + q * 8]);
    bf16x8v ha2 = *reinterpret_cast<const bf16x8v*>(&htile[arow * HT_LD + 2 * 32 + q * 8]);
    bf16x8v ha3 = *reinterpret_cast<const bf16x8v*>(&htile[arow * HT_LD + 3 * 32 + q * 8]);
    {
        int d = (wv >> 2) * 16 + m;
        bf16x8v bw0 = *reinterpret_cast<const bf16x8v*>(w2tb + d * D_HIDF + 0 * 32 + q * 8);
        bf16x8v bw1 = *reinterpret_cast<const bf16x8v*>(w2tb + d * D_HIDF + 1 * 32 + q * 8);
        bf16x8v bw2 = *reinterpret_cast<const bf16x8v*>(w2tb + d * D_HIDF + 2 * 32 + q * 8);
        bf16x8v bw3 = *reinterpret_cast<const bf16x8v*>(w2tb + d * D_HIDF + 3 * 32 + q * 8);
        f32x4 acc = {0.f, 0.f, 0.f, 0.f};
        acc = __builtin_amdgcn_mfma_f32_16x16x32_bf16(ha0, bw0, acc, 0, 0, 0);
        acc = __builtin_amdgcn_mfma_f32_16x16x32_bf16(ha1, bw1, acc, 0, 0, 0);
        acc = __builtin_amdgcn_mfma_f32_16x16x32_bf16(ha2, bw2, acc, 0, 0, 0);
        acc = __builtin_amdgcn_mfma_f32_16x16x32_bf16(ha3, bw3, acc, 0, 0, 0);
        float bv = b2v[d];
#pragma unroll
        for (int r = 0; r < 4; r++) {
            int node = nb + hrow0 + r;
            if (node < N_NODES) out[(size_t)node * D_INF + d] = acc[r] + bv;
        }
    }
}

// ---------------------------------------------------------------------------
// Fallback path (ws too small): atomic scatter + standalone MLP (proven r8).
// ---------------------------------------------------------------------------

#define W1_LD 72
#define W2_LD 136

__global__ void __launch_bounds__(256) mlp_mfma_kernel(
    const ushort* __restrict__ aggb, const ushort* __restrict__ w1tb,
    const float* __restrict__ b1v, const ushort* __restrict__ w2tb,
    const float* __restrict__ b2v, float* __restrict__ out)
{
    __shared__ __align__(16) ushort atile[64 * AT_LD];
    __shared__ __align__(16) ushort w1s[128 * W1_LD];
    __shared__ __align__(16) ushort w2s[64 * W2_LD];
    __shared__ __align__(16) ushort htile[64 * HT_LD];

    int tid = threadIdx.x;
    int lane = tid & 63;
    int wv = tid >> 6;
    int nb = blockIdx.x * 64;

#pragma unroll
    for (int c = 0; c < 2; c++) {
        int chunk = tid + c * 256;
        int row = chunk >> 3;
        int col = (chunk & 7) * 8;
        ulonglong2 v;
        v.x = 0; v.y = 0;
        if (nb + row < N_NODES)
            v = *reinterpret_cast<const ulonglong2*>(aggb + (size_t)(nb + row) * D_INF + col);
        *reinterpret_cast<ulonglong2*>(&atile[row * AT_LD + col]) = v;
    }
#pragma unroll
    for (int c = 0; c < 4; c++) {
        int chunk = tid + c * 256;
        int row = chunk >> 3;
        int col = (chunk & 7) * 8;
        *reinterpret_cast<ulonglong2*>(&w1s[row * W1_LD + col]) =
            *reinterpret_cast<const ulonglong2*>(w1tb + row * 64 + col);
    }
#pragma unroll
    for (int c = 0; c < 4; c++) {
        int chunk = tid + c * 256;
        int row = chunk >> 4;
        int col = (chunk & 15) * 8;
        *reinterpret_cast<ulonglong2*>(&w2s[row * W2_LD + col]) =
            *reinterpret_cast<const ulonglong2*>(w2tb + row * 128 + col);
    }
    __syncthreads();

    int q = lane >> 4;
    int m = lane & 15;
    int arow = wv * 16 + m;
    int hrow0 = wv * 16 + q * 4;

    bf16x8v a0 = *reinterpret_cast<const bf16x8v*>(&atile[arow * AT_LD + q * 8]);
    bf16x8v a1 = *reinterpret_cast<const bf16x8v*>(&atile[arow * AT_LD + 32 + q * 8]);
#pragma unroll
    for (int jt = 0; jt < 8; jt++) {
        int j = jt * 16 + m;
        bf16x8v bf0 = *reinterpret_cast<const bf16x8v*>(&w1s[j * W1_LD + q * 8]);
        bf16x8v bf1 = *reinterpret_cast<const bf16x8v*>(&w1s[j * W1_LD + 32 + q * 8]);
        f32x4 acc = {0.f, 0.f, 0.f, 0.f};
        acc = __builtin_amdgcn_mfma_f32_16x16x32_bf16(a0, bf0, acc, 0, 0, 0);
        acc = __builtin_amdgcn_mfma_f32_16x16x32_bf16(a1, bf1, acc, 0, 0, 0);
        float bv = b1v[j];
#pragma unroll
        for (int r = 0; r < 4; r++) {
            float hv = fmaxf(acc[r] + bv, 0.f);
            htile[(hrow0 + r) * HT_LD + j] = f2bf(hv);
        }
    }

    bf16x8v ha0 = *reinterpret_cast<const bf16x8v*>(&htile[arow * HT_LD + 0 * 32 + q * 8]);
    bf16x8v ha1 = *reinterpret_cast<const bf16x8v*>(&htile[arow * HT_LD + 1 * 32 + q * 8]);
    bf16x8v ha2 = *reinterpret_cast<const bf16x8v*>(&htile[arow * HT_LD + 2 * 32 + q * 8]);
    bf16x8v ha3 = *reinterpret_cast<const bf16x8v*>(&htile[arow * HT_LD + 3 * 32 + q * 8]);
#pragma unroll
    for (int dt = 0; dt < 4; dt++) {
        int d = dt * 16 + m;
        f32x4 acc = {0.f, 0.f, 0.f, 0.f};
        bf16x8v bw0 = *reinterpret_cast<const bf16x8v*>(&w2s[d * W2_LD + 0 * 32 + q * 8]);
        bf16x8v bw1 = *reinterpret_cast<const bf16x8v*>(&w2s[d * W2_LD + 1 * 32 + q * 8]);
        bf16x8v bw2 = *reinterpret_cast<const bf16x8v*>(&w2s[d * W2_LD + 2 * 32 + q * 8]);
        bf16x8v bw3 = *reinterpret_cast<const bf16x8v*>(&w2s[d * W2_LD + 3 * 32 + q * 8]);
        acc = __builtin_amdgcn_mfma_f32_16x16x32_bf16(ha0, bw0, acc, 0, 0, 0);
        acc = __builtin_amdgcn_mfma_f32_16x16x32_bf16(ha1, bw1, acc, 0, 0, 0);
        acc = __builtin_amdgcn_mfma_f32_16x16x32_bf16(ha2, bw2, acc, 0, 0, 0);
        acc = __builtin_amdgcn_mfma_f32_16x16x32_bf16(ha3, bw3, acc, 0, 0, 0);
        float bv = b2v[d];
#pragma unroll
        for (int r = 0; r < 4; r++) {
            int node = nb + hrow0 + r;
            if (node < N_NODES) out[(size_t)node * D_INF + d] = acc[r] + bv;
        }
    }
}

__global__ void init_agg_kernel(const float* __restrict__ x, float* __restrict__ agg) {
    int i = blockIdx.x * blockDim.x + threadIdx.x;
    int n4 = N_NODES * D_INF / 4;
    if (i < n4) {
        reinterpret_cast<float4*>(agg)[i] = reinterpret_cast<const float4*>(x)[i];
    }
}

__global__ void scatter_kernel(const float* __restrict__ x,
                               const int* __restrict__ src,
                               const int* __restrict__ dst,
                               float* __restrict__ agg) {
    int tid = blockIdx.x * blockDim.x + threadIdx.x;
    int e = tid >> 6;
    int d = tid & 63;
    if (e < N_EDGES) {
        atomicAdd(&agg[(size_t)dst[e] * D_INF + d], x[(size_t)src[e] * D_INF + d]);
    }
}

__global__ void cvt_agg_kernel(const float* __restrict__ agg32, ushort* __restrict__ aggb) {
    int i = blockIdx.x * blockDim.x + threadIdx.x;
    if (i < N_NODES * D_INF) aggb[i] = f2bf(agg32[i]);
}

__global__ void prep_weights_only_kernel(const float* __restrict__ W1,
                                         const float* __restrict__ W2,
                                         ushort* __restrict__ w1tb,
                                         ushort* __restrict__ w2tb) {
    int i = blockIdx.x * blockDim.x + threadIdx.x;
    if (i < D_INF * D_HIDF) {
        int j = i >> 6, l = i & 63;
        w1tb[i] = f2bf(W1[l * D_HIDF + j]);
        int d = i >> 7, jj = i & 127;
        w2tb[i] = f2bf(W2[jj * D_INF + d]);
    }
}

// ---------------------------------------------------------------------------

extern "C" void kernel_launch(void* const* d_in, const int* in_sizes, int n_in,
                              void* d_out, int out_size, void* d_ws, size_t ws_size,
                              hipStream_t stream) {
    const float* x   = (const float*)d_in[0];
    const int* edge  = (const int*)d_in[1];   // [2, E]: src = edge, dst = edge + E
    const float* W1  = (const float*)d_in[2];
    const float* b1  = (const float*)d_in[3];
    const float* W2  = (const float*)d_in[4];
    const float* b2  = (const float*)d_in[5];
    float* out       = (float*)d_out;

    const int* src = edge;
    const int* dst = edge + N_EDGES;

    // Workspace layout (fast path ~19.3 MB; observed ws ~268 MB):
    //   w1tb / w2tb : 8192 bf16 each (32 KB)
    //   xb     : N*64 bf16 (6.4 MB)
    //   gcursor: NBUCKET ints
    //   binned : NBUCKET*CAP uints (12.8 MB)
    //   fallback overlay: agg32 (f32, at xb) + aggb (bf16, after binned)
    ushort* w1tb   = (ushort*)d_ws;
    ushort* w2tb   = w1tb + D_INF * D_HIDF;
    ushort* xb     = w2tb + D_INF * D_HIDF;
    int* gcursor   = (int*)(xb + (size_t)N_NODES * D_INF);
    unsigned int* binned = (unsigned int*)(gcursor + NBUCKET);
    float* agg32   = (float*)xb;
    ushort* aggb   = (ushort*)(binned + (size_t)NBUCKET * CAP);

    size_t needed_full = (uintptr_t)(binned + (size_t)NBUCKET * CAP) - (uintptr_t)d_ws;
    size_t needed_fb   = (uintptr_t)(aggb + (size_t)N_NODES * D_INF) - (uintptr_t)d_ws;

    if (ws_size >= needed_full) {
        int prep_total = CVT_N + PREP_N + NBUCKET;
        prep_kernel<<<(prep_total + 255) / 256, 256, 0, stream>>>(
            x, xb, W1, W2, w1tb, w2tb, gcursor);
        sortfill_kernel<<<NCHUNK, 256, 0, stream>>>(src, dst, gcursor, binned);
        mega_kernel<<<NBUCKET, 1024, 0, stream>>>(
            xb, binned, gcursor, w1tb, b1, w2tb, b2, out);
    } else if (ws_size >= needed_fb) {
        prep_weights_only_kernel<<<(PREP_N + 255) / 256, 256, 0, stream>>>(W1, W2, w1tb, w2tb);
        int n4 = N_NODES * D_INF / 4;
        init_agg_kernel<<<(n4 + 255) / 256, 256, 0, stream>>>(x, agg32);
        int work = N_EDGES * D_INF;
        scatter_kernel<<<(work + 255) / 256, 256, 0, stream>>>(x, src, dst, agg32);
        cvt_agg_kernel<<<(N_NODES * D_INF + 255) / 256, 256, 0, stream>>>(agg32, aggb);
        mlp_mfma_kernel<<<(N_NODES + 63) / 64, 256, 0, stream>>>(aggb, w1tb, b1, w2tb, b2, out);
    }
}